// Round 13
// baseline (327.627 us; speedup 1.0000x reference)
//
#include <hip/hip_runtime.h>
#include <hip/hip_bf16.h>
#include <type_traits>

#define LEAKY 0.2f
#define SC 512  // scan chunk per block

using h2_t = __attribute__((ext_vector_type(2))) _Float16;
using h4_t = __attribute__((ext_vector_type(4))) _Float16;
using f16x8 = __attribute__((ext_vector_type(8))) _Float16;
using f32x4 = __attribute__((ext_vector_type(4))) float;

// ---------------- CSR build ----------------

__global__ __launch_bounds__(256) void count_kernel(const int* __restrict__ ei,
                                                    int* __restrict__ cnt,
                                                    int E, int ET) {
    int e = blockIdx.x * 256 + threadIdx.x;
    if (e >= ET) return;
    int d = (e < E) ? ei[E + e] : (e - E);
    atomicAdd(&cnt[d], 1);
}

// level-1: per-block (512-elem chunk) sums of cnt
__global__ __launch_bounds__(256) void psum_kernel(const int* __restrict__ cnt,
                                                   int* __restrict__ bsum, int N) {
    int b = blockIdx.x, tid = threadIdx.x;
    int base = b * SC;
    int s = 0;
#pragma unroll
    for (int p = 0; p < 2; p++) {
        int i = base + p * 256 + tid;
        if (i < N) s += cnt[i];
    }
#pragma unroll
    for (int m = 1; m < 64; m <<= 1) s += __shfl_xor(s, m);
    __shared__ int ws[4];
    if ((tid & 63) == 0) ws[tid >> 6] = s;
    __syncthreads();
    if (tid == 0) bsum[b] = ws[0] + ws[1] + ws[2] + ws[3];
}

// level-2: block-local exclusive scan + block offset -> rowptr; cnt becomes cursor.
__global__ __launch_bounds__(256) void scanw_kernel(int* __restrict__ cnt,
                                                    const int* __restrict__ bsum,
                                                    int* __restrict__ rowptr,
                                                    int N, int B) {
    int b = blockIdx.x, tid = threadIdx.x;
    int off = 0;
    for (int j = 0; j < b; j++) off += bsum[j];  // uniform, L2-resident

    __shared__ int lds[256];
    int base = b * SC;
    int i0 = base + 2 * tid, i1 = i0 + 1;
    int v0 = (i0 < N) ? cnt[i0] : 0;
    int v1 = (i1 < N) ? cnt[i1] : 0;
    lds[tid] = v0 + v1;
    __syncthreads();
#pragma unroll
    for (int o = 1; o < 256; o <<= 1) {
        int v = (tid >= o) ? lds[tid - o] : 0;
        __syncthreads();
        lds[tid] += v;
        __syncthreads();
    }
    int excl = (tid == 0) ? 0 : lds[tid - 1];
    int p0 = off + excl;
    int p1 = p0 + v0;
    if (i0 < N) { rowptr[i0] = p0; cnt[i0] = p0; }
    if (i1 < N) { rowptr[i1] = p1; cnt[i1] = p1; }
    if (b == B - 1 && tid == 255) rowptr[N] = off + lds[255];
}

__global__ __launch_bounds__(256) void scatter_kernel(const int* __restrict__ ei,
                                                      int* __restrict__ cursor,
                                                      int* __restrict__ perm,
                                                      int E, int ET) {
    int e = blockIdx.x * 256 + threadIdx.x;
    if (e >= ET) return;
    int s, d;
    if (e < E) { s = ei[e]; d = ei[E + e]; } else { s = e - E; d = s; }
    int pos = atomicAdd(&cursor[d], 1);  // absolute position
    perm[pos] = s;  // store src node id directly
}

// ---------------- fused pre-pass: x->fp16 + W1/W2/W3 transpose->fp16 ----------------
// Wt layout: Wt1[128*128] | Wt2[128*128] | Wt3[320*128], Wt_l[n][k] = W_l[k][n].

__global__ __launch_bounds__(256) void prep_kernel(const float* __restrict__ x,
                                                   _Float16* __restrict__ xh,
                                                   const float* __restrict__ W1,
                                                   const float* __restrict__ W2,
                                                   const float* __restrict__ W3,
                                                   _Float16* __restrict__ Wt,
                                                   int n4) {
    int i = blockIdx.x * 256 + threadIdx.x;
    if (i < n4) {
        float4 v = ((const float4*)x)[i];
        h4_t o = {(_Float16)v.x, (_Float16)v.y, (_Float16)v.z, (_Float16)v.w};
        ((h4_t*)xh)[i] = o;
        return;
    }
    int j = i - n4;
    if (j >= (128 + 128 + 320) * 128) return;
    if (j < 128 * 128) {
        int n = j >> 7, k = j & 127;
        Wt[j] = (_Float16)W1[k * 128 + n];
    } else if (j < 2 * 128 * 128) {
        int jj = j - 128 * 128;
        int n = jj >> 7, k = jj & 127;
        Wt[j] = (_Float16)W2[k * 128 + n];
    } else {
        int jj = j - 2 * 128 * 128;
        int n = jj >> 7, k = jj & 127;
        Wt[j] = (_Float16)W3[k * 320 + n];
    }
}

// ---------------- MFMA GEMM: Hh[M,HC] = fp16(A[M,128] @ Wt^T) ----------------

template <int C, bool FUSE>
__global__ __launch_bounds__(256) void mgemm_kernel(const _Float16* __restrict__ A,
                                                    const _Float16* __restrict__ Wt,
                                                    const float* __restrict__ As_,
                                                    const float* __restrict__ Ad_,
                                                    _Float16* __restrict__ Hh,
                                                    float* __restrict__ es,
                                                    float* __restrict__ ed,
                                                    int M) {
    constexpr int K = 128;
    constexpr int HC = 8 * C;
    __shared__ __align__(16) unsigned char lds[128 * 128 + 64 * 128];  // 24 KB
    unsigned char* Asm = lds;                 // [128 rows][8 granules of 16B]
    unsigned char* Bsm = lds + 128 * 128;     // [64 cols][8 granules]

    int tid = threadIdx.x;
    int lane = tid & 63;
    int wid = tid >> 6;
    int wm = wid >> 1, wn = wid & 1;
    int m0 = blockIdx.x * 128, n0 = blockIdx.y * 64;

    f32x4 acc[4][2] = {};

    int fr = lane & 15;   // row/col within fragment
    int fk = lane >> 4;   // k-granule within 32-k chunk (0..3)

    for (int k0 = 0; k0 < K; k0 += 64) {
#pragma unroll
        for (int p = 0; p < 4; p++) {
            int g = tid + p * 256;
            int row = g >> 3, kg = g & 7;
            uint4 v = {0, 0, 0, 0};
            int grow = m0 + row;
            if (grow < M) v = *(const uint4*)&A[(size_t)grow * K + k0 + kg * 8];
            *(uint4*)&Asm[row * 128 + ((kg ^ (row & 7)) << 4)] = v;
        }
#pragma unroll
        for (int p = 0; p < 2; p++) {
            int g = tid + p * 256;
            int col = g >> 3, kg = g & 7;
            uint4 v = *(const uint4*)&Wt[(size_t)(n0 + col) * K + k0 + kg * 8];
            *(uint4*)&Bsm[col * 128 + ((kg ^ (col & 7)) << 4)] = v;
        }
        __syncthreads();

#pragma unroll
        for (int kf = 0; kf < 2; kf++) {
            int kg = kf * 4 + fk;
            f16x8 af[4], bf[2];
#pragma unroll
            for (int mf = 0; mf < 4; mf++) {
                int row = wm * 64 + mf * 16 + fr;
                af[mf] = *(f16x8*)&Asm[row * 128 + ((kg ^ (row & 7)) << 4)];
            }
#pragma unroll
            for (int nf = 0; nf < 2; nf++) {
                int col = wn * 32 + nf * 16 + fr;
                bf[nf] = *(f16x8*)&Bsm[col * 128 + ((kg ^ (col & 7)) << 4)];
            }
#pragma unroll
            for (int mf = 0; mf < 4; mf++)
#pragma unroll
                for (int nf = 0; nf < 2; nf++)
                    acc[mf][nf] = __builtin_amdgcn_mfma_f32_16x16x32_f16(
                        af[mf], bf[nf], acc[mf][nf], 0, 0, 0);
        }
        __syncthreads();
    }

    // ---- epilogue: restage via LDS (fp16 [128][64]) ----
    _Float16* Es = (_Float16*)lds;
    int crow = wm * 64 + (lane >> 4) * 4;
    int ccol = wn * 32 + (lane & 15);
#pragma unroll
    for (int mf = 0; mf < 4; mf++)
#pragma unroll
        for (int nf = 0; nf < 2; nf++)
#pragma unroll
            for (int j = 0; j < 4; j++)
                Es[(crow + mf * 16 + j) * 64 + ccol + nf * 16] = (_Float16)acc[mf][nf][j];
    __syncthreads();

#pragma unroll
    for (int p = 0; p < 4; p++) {
        int g = tid + p * 256;
        int row = g >> 3, cg = g & 7;
        int grow = m0 + row;
        if (grow < M)
            *(uint4*)&Hh[(size_t)grow * HC + n0 + cg * 8] = *(uint4*)&Es[row * 64 + cg * 8];
    }

    if constexpr (FUSE) {
        // C==16: this 64-col block holds 4 whole heads
#pragma unroll
        for (int p = 0; p < 2; p++) {
            int t = tid + p * 256;
            int row = t >> 2, hq = t & 3;
            int grow = m0 + row;
            int h = (n0 >> 4) + hq;
            const _Float16* rp = &Es[row * 64 + hq * 16];
            const float* ap = &As_[h * 16];
            const float* dp = &Ad_[h * 16];
            float s = 0.f, d = 0.f;
#pragma unroll
            for (int c2 = 0; c2 < 16; c2++) {
                float v = (float)rp[c2];
                s = fmaf(v, ap[c2], s);
                d = fmaf(v, dp[c2], d);
            }
            if (grow < M) {
                es[grow * 8 + h] = s;
                ed[grow * 8 + h] = d;
            }
        }
    }
}

// ---------------- per-node attention scores (fp16 features) ----------------

template <int C>
__global__ __launch_bounds__(256) void attn_score_kernel(const _Float16* __restrict__ Hf,
                                                         const float* __restrict__ as_,
                                                         const float* __restrict__ ad_,
                                                         float* __restrict__ es,
                                                         float* __restrict__ ed, int N) {
    int i = blockIdx.x * 256 + threadIdx.x;
    if (i >= N * 8) return;
    int n = i >> 3, h = i & 7;
    const _Float16* hp = Hf + (size_t)n * 8 * C + h * C;
    const float* ap = as_ + h * C;
    const float* bp = ad_ + h * C;
    float s = 0.f, d = 0.f;
#pragma unroll
    for (int c = 0; c < C / 2; c++) {
        h2_t v = *(const h2_t*)&hp[2 * c];
        float v0 = (float)v[0], v1 = (float)v[1];
        s = fmaf(v0, ap[2 * c], s);
        d = fmaf(v0, bp[2 * c], d);
        s = fmaf(v1, ap[2 * c + 1], s);
        d = fmaf(v1, bp[2 * c + 1], d);
    }
    es[i] = s;
    ed[i] = d;
}

// ---------------- agg16: 2 dsts per wave, h4 gathers (C=16, HC=128) ----------------
// Lanes 0-31 own dst A, 32-63 own dst B. Each lane owns 4 features (one head:
// head = l32>>2). Per half: head = lane&7, eslot = (lane>>3)&3 (4 edges/slot-reg).
// Per chunk (8 edges/dst): 2 slot-regs of (src,alpha), then 8 staged h4 loads
// (each load instruction fetches both halves' rows). Softmax reduce within the
// 32-lane half (xor 8,16). No stability shift (scores O(1)-bounded).

__global__ __launch_bounds__(256) void agg16_kernel(const _Float16* __restrict__ Hf,
                                                    const float* __restrict__ es,
                                                    const float* __restrict__ ed,
                                                    const int* __restrict__ rowptr,
                                                    const int* __restrict__ perm,
                                                    const float* __restrict__ bias,
                                                    _Float16* __restrict__ Out, int N) {
    int lane = threadIdx.x & 63;
    int wid = threadIdx.x >> 6;
    int half = lane >> 5;
    int l32 = lane & 31;
    int d = blockIdx.x * 8 + wid * 2 + half;
    bool active = d < N;
    int start = 0, end = 0;
    if (active) { start = rowptr[d]; end = rowptr[d + 1]; }
    int len = end - start;
    int lenmax = max(len, __shfl_xor(len, 32));
    int iters = (lenmax + 7) >> 3;

    int h8 = lane & 7;
    int eslot = (lane >> 3) & 3;
    float edh = active ? ed[d * 8 + h8] : 0.f;
    int hh03 = l32 >> 2;  // head owning this lane's 4 features

    float acc0 = 0.f, acc1 = 0.f, acc2 = 0.f, acc3 = 0.f;
    float dsum = 0.f;

    for (int it = 0; it < iters; ++it) {
        int q0 = start + it * 8;
        int qq0 = q0 + eslot, qq1 = q0 + 4 + eslot;
        int s_l0 = 0, s_l1 = 0;
        float a_l0 = 0.f, a_l1 = 0.f;
        if (qq0 < end) {
            s_l0 = perm[qq0];
            float v = es[s_l0 * 8 + h8] + edh;
            v = (v >= 0.f) ? v : LEAKY * v;
            a_l0 = __expf(v);
        }
        if (qq1 < end) {
            s_l1 = perm[qq1];
            float v = es[s_l1 * 8 + h8] + edh;
            v = (v >= 0.f) ? v : LEAKY * v;
            a_l1 = __expf(v);
        }
        dsum += a_l0 + a_l1;

        h4_t hv[8];
#pragma unroll
        for (int e = 0; e < 8; e++) {
            int sA = (e < 4) ? __builtin_amdgcn_readlane(s_l0, e * 8)
                             : __builtin_amdgcn_readlane(s_l1, (e - 4) * 8);
            int sB = (e < 4) ? __builtin_amdgcn_readlane(s_l0, 32 + e * 8)
                             : __builtin_amdgcn_readlane(s_l1, 32 + (e - 4) * 8);
            int s = half ? sB : sA;
            hv[e] = *(const h4_t*)&Hf[(size_t)s * 128 + 4 * l32];
        }
#pragma unroll
        for (int e = 0; e < 8; e++) {
            int bidx = (lane & 32) + (e & 3) * 8 + hh03;
            float a = (e < 4) ? __shfl(a_l0, bidx) : __shfl(a_l1, bidx);
            acc0 = fmaf(a, (float)hv[e][0], acc0);
            acc1 = fmaf(a, (float)hv[e][1], acc1);
            acc2 = fmaf(a, (float)hv[e][2], acc2);
            acc3 = fmaf(a, (float)hv[e][3], acc3);
        }
    }

    // per-head denom within the half
    dsum += __shfl_xor(dsum, 8);
    dsum += __shfl_xor(dsum, 16);
    float rden = 1.0f / (dsum + 1e-16f);
    float r = __shfl(rden, (lane & 32) + hh03);

    if (active) {
        float4 bv = *(const float4*)&bias[4 * l32];
        float v0 = acc0 * r + bv.x;
        float v1 = acc1 * r + bv.y;
        float v2 = acc2 * r + bv.z;
        float v3 = acc3 * r + bv.w;
        v0 = (v0 > 0.f) ? v0 : expm1f(v0);  // ELU
        v1 = (v1 > 0.f) ? v1 : expm1f(v1);
        v2 = (v2 > 0.f) ? v2 : expm1f(v2);
        v3 = (v3 > 0.f) ? v3 : expm1f(v3);
        h4_t o = {(_Float16)v0, (_Float16)v1, (_Float16)v2, (_Float16)v3};
        *(h4_t*)&Out[(size_t)d * 128 + 4 * l32] = o;
    }
}

// ---------------- agg40 (final layer): wave-per-dst, 16-edge chunks ----------------
// (R6 branchless form — verified fastest; at the random-gather pattern ceiling.)

__global__ __launch_bounds__(256) void agg40_kernel(const _Float16* __restrict__ Hf,
                                                    const float* __restrict__ es,
                                                    const float* __restrict__ ed,
                                                    const int* __restrict__ rowptr,
                                                    const int* __restrict__ perm,
                                                    const float* __restrict__ bias,
                                                    float* __restrict__ Out, int N) {
    constexpr int C = 40;
    constexpr int HC = 320;
    __shared__ float sfeat[4][HC];
    int lane = threadIdx.x & 63;
    int wid = threadIdx.x >> 6;
    int d = blockIdx.x * 4 + wid;
    bool active = d < N;
    int start = 0, end = 0;
    if (active) { start = rowptr[d]; end = rowptr[d + 1]; }
    start = __builtin_amdgcn_readfirstlane(start);
    end = __builtin_amdgcn_readfirstlane(end);
    int h8 = lane & 7;
    int eslot = lane >> 3;
    float edh = active ? ed[d * 8 + h8] : 0.f;

    int hh03 = (4 * lane) / C;
    int hh4 = (256 + lane) / C;

    float acc[5] = {0.f, 0.f, 0.f, 0.f, 0.f};
    float dsum = 0.f;
    for (int q0 = start; q0 < end; q0 += 16) {
        int qq0 = q0 + eslot, qq1 = q0 + 8 + eslot;
        int s_l0 = 0, s_l1 = 0;
        float a_l0 = 0.f, a_l1 = 0.f;
        if (qq0 < end) {
            s_l0 = perm[qq0];
            float v = es[s_l0 * 8 + h8] + edh;
            v = (v >= 0.f) ? v : LEAKY * v;
            a_l0 = __expf(v);
        }
        if (qq1 < end) {
            s_l1 = perm[qq1];
            float v = es[s_l1 * 8 + h8] + edh;
            v = (v >= 0.f) ? v : LEAKY * v;
            a_l1 = __expf(v);
        }
        dsum += a_l0 + a_l1;

        h4_t hv[16];
        _Float16 hx[16];
#pragma unroll
        for (int e = 0; e < 16; e++) {
            int s = (e < 8) ? __builtin_amdgcn_readlane(s_l0, e * 8)
                            : __builtin_amdgcn_readlane(s_l1, (e - 8) * 8);
            const _Float16* hp = Hf + (size_t)s * HC;
            hv[e] = *(const h4_t*)&hp[4 * lane];
            hx[e] = hp[256 + lane];
        }
#pragma unroll
        for (int e = 0; e < 16; e++) {
            float a03, a4;
            if (e < 8) {
                a03 = __shfl(a_l0, e * 8 + hh03);
                a4 = __shfl(a_l0, e * 8 + hh4);
            } else {
                a03 = __shfl(a_l1, (e - 8) * 8 + hh03);
                a4 = __shfl(a_l1, (e - 8) * 8 + hh4);
            }
            acc[0] = fmaf(a03, (float)hv[e][0], acc[0]);
            acc[1] = fmaf(a03, (float)hv[e][1], acc[1]);
            acc[2] = fmaf(a03, (float)hv[e][2], acc[2]);
            acc[3] = fmaf(a03, (float)hv[e][3], acc[3]);
            acc[4] = fmaf(a4, (float)hx[e], acc[4]);
        }
    }

#pragma unroll
    for (int m = 8; m < 64; m <<= 1) dsum += __shfl_xor(dsum, m);
    float rden = 1.0f / (dsum + 1e-16f);

    float r03 = __shfl(rden, hh03);
    float r4 = __shfl(rden, hh4);
#pragma unroll
    for (int j = 0; j < 4; j++) sfeat[wid][4 * lane + j] = acc[j] * r03;
    sfeat[wid][256 + lane] = acc[4] * r4;
    __syncthreads();
    if (active && lane < C) {
        float s = 0.f;
#pragma unroll
        for (int h = 0; h < 8; h++) s += sfeat[wid][h * C + lane];
        Out[(size_t)d * C + lane] = s * 0.125f + bias[lane];
    }
}

// ---------------- launch ----------------

extern "C" void kernel_launch(void* const* d_in, const int* in_sizes, int n_in,
                              void* d_out, int out_size, void* d_ws, size_t ws_size,
                              hipStream_t stream) {
    const float* x   = (const float*)d_in[0];
    const int*   ei  = (const int*)d_in[1];
    const float* W1  = (const float*)d_in[2];
    const float* a1s = (const float*)d_in[3];
    const float* a1d = (const float*)d_in[4];
    const float* b1  = (const float*)d_in[5];
    const float* W2  = (const float*)d_in[6];
    const float* a2s = (const float*)d_in[7];
    const float* a2d = (const float*)d_in[8];
    const float* b2  = (const float*)d_in[9];
    const float* W3  = (const float*)d_in[10];
    const float* a3s = (const float*)d_in[11];
    const float* a3d = (const float*)d_in[12];
    const float* b3  = (const float*)d_in[13];
    float* out = (float*)d_out;

    const int N = in_sizes[0] / 128;
    const int E = in_sizes[1] / 2;
    const int ET = E + N;
    const int B = (N + SC - 1) / SC;

    char* p = (char*)d_ws;
    _Float16* hbuf = (_Float16*)p; p += (size_t)N * 320 * 2;
    _Float16* xbuf = (_Float16*)p; p += (size_t)N * 128 * 2;
    float* es    = (float*)p; p += (size_t)N * 8 * 4;
    float* edd   = (float*)p; p += (size_t)N * 8 * 4;
    int* cnt     = (int*)p;   p += (size_t)N * 4;
    int* rowptr  = (int*)p;   p += (size_t)(N + 1) * 4;
    int* perm    = (int*)p;   p += (size_t)ET * 4;
    int* bsum    = (int*)p;   p += (size_t)B * 4;
    _Float16* Wt1 = (_Float16*)p; p += 128 * 128 * 2;
    _Float16* Wt2 = (_Float16*)p; p += 128 * 128 * 2;
    _Float16* Wt3 = (_Float16*)p; p += 320 * 128 * 2;

    // CSR build (shared by all 3 layers)
    hipMemsetAsync(cnt, 0, (size_t)N * 4, stream);
    count_kernel<<<(ET + 255) / 256, 256, 0, stream>>>(ei, cnt, E, ET);
    psum_kernel<<<B, 256, 0, stream>>>(cnt, bsum, N);
    scanw_kernel<<<B, 256, 0, stream>>>(cnt, bsum, rowptr, N, B);  // cnt -> cursor
    scatter_kernel<<<(ET + 255) / 256, 256, 0, stream>>>(ei, cnt, perm, E, ET);

    // fused pre-pass: x->fp16 + all W transposes
    int n4 = N * 32;
    int prep_total = n4 + (128 + 128 + 320) * 128;
    prep_kernel<<<(prep_total + 255) / 256, 256, 0, stream>>>(x, xbuf, W1, W2, W3, Wt1, n4);

    int agg16_grid = (N + 7) / 8;
    int agg40_grid = (N + 3) / 4;
    int nh_grid = (N * 8 + 255) / 256;
    int gx = (N + 127) / 128;
    dim3 g128(gx, 2);   // HC=128
    dim3 g320(gx, 5);   // HC=320

    // layer 1: GAT(128 -> 8x16, concat) + ELU  (scores fused, MFMA)
    mgemm_kernel<16, true><<<g128, 256, 0, stream>>>(xbuf, Wt1, a1s, a1d, hbuf, es, edd, N);
    agg16_kernel<<<agg16_grid, 256, 0, stream>>>(hbuf, es, edd, rowptr, perm, b1, xbuf, N);

    // layer 2: GAT(128 -> 8x16, concat) + ELU
    mgemm_kernel<16, true><<<g128, 256, 0, stream>>>(xbuf, Wt2, a2s, a2d, hbuf, es, edd, N);
    agg16_kernel<<<agg16_grid, 256, 0, stream>>>(hbuf, es, edd, rowptr, perm, b2, xbuf, N);

    // layer 3: GAT(128 -> 8x40, mean over heads)
    mgemm_kernel<40, false><<<g320, 256, 0, stream>>>(xbuf, Wt3, nullptr, nullptr, hbuf, nullptr, nullptr, N);
    attn_score_kernel<40><<<nh_grid, 256, 0, stream>>>(hbuf, a3s, a3d, es, edd, N);
    agg40_kernel<<<agg40_grid, 256, 0, stream>>>(hbuf, es, edd, rowptr, perm, b3, out, N);
}